// Round 4
// baseline (2901.700 us; speedup 1.0000x reference)
//
#include <hip/hip_runtime.h>
#include <stdint.h>

typedef unsigned short u16;
typedef unsigned int   u32;
typedef __attribute__((ext_vector_type(8))) short  short8;
typedef __attribute__((ext_vector_type(4))) float  floatx4;

#define Bz   16
#define Mm   1024
#define Nn   1024
#define Dd   1024
#define HIDh 512
#define INV_SQRT_D 0.03125f
#define NEGINF (-1.0e9f)
#define BMDc  ((size_t)Bz * Mm * Dd)

__device__ __forceinline__ float bf2f(u16 h) {
    union { u32 u; float f; } c; c.u = ((u32)h) << 16; return c.f;
}
__device__ __forceinline__ u16 f2bf(float f) {
    union { float f; u32 u; } c; c.f = f;
    u32 u = c.u;
    return (u16)((u + 0x7FFFu + ((u >> 16) & 1u)) >> 16);
}

__device__ __forceinline__ float waveMax(float v) {
#pragma unroll
    for (int o = 32; o > 0; o >>= 1) v = fmaxf(v, __shfl_xor(v, o));
    return v;
}
__device__ __forceinline__ float waveSum(float v) {
#pragma unroll
    for (int o = 32; o > 0; o >>= 1) v += __shfl_xor(v, o);
    return v;
}

// ============ C = A * B^T, fp32 sources converted to bf16 at staging, bf16 out ============
// A: MxK row-major fp32, B: NxK row-major fp32. 128x128 tile, 4 waves, 4x4 MFMA 16x16x32.
template <bool BIAS>
__global__ __launch_bounds__(256, 2) void gemm_bt_f32(
    const float* __restrict__ A, const float* __restrict__ Bm, const float* __restrict__ bias,
    u16* __restrict__ C, int K, int ldc, long sA, long sB, long sC)
{
    __shared__ __align__(16) u16 lA[128 * 32];
    __shared__ __align__(16) u16 lB[128 * 32];
    const int tid = threadIdx.x;
    const int lane = tid & 63;
    const int fr = lane & 15, fq = lane >> 4;
    const int wv = tid >> 6;
    const int tileM = blockIdx.x * 128, tileN = blockIdx.y * 128;
    A  += (long)blockIdx.z * sA;
    Bm += (long)blockIdx.z * sB;

    floatx4 acc[4][4];
#pragma unroll
    for (int i = 0; i < 4; ++i)
#pragma unroll
        for (int j = 0; j < 4; ++j) acc[i][j] = (floatx4){0.f, 0.f, 0.f, 0.f};

    const int waveM = (wv >> 1) * 64, waveN = (wv & 1) * 64;

    for (int k0 = 0; k0 < K; k0 += 32) {
        float4 ra[2][2], rb[2][2];
#pragma unroll
        for (int i = 0; i < 2; ++i) {
            const int chunk = i * 256 + tid;          // 8-elem chunk, row-major [128][32]
            const int r = chunk >> 2, c = (chunk & 3) << 3;
            const float* pa = A  + (size_t)(tileM + r) * K + (k0 + c);
            const float* pb = Bm + (size_t)(tileN + r) * K + (k0 + c);
            ra[i][0] = *(const float4*)pa; ra[i][1] = *(const float4*)(pa + 4);
            rb[i][0] = *(const float4*)pb; rb[i][1] = *(const float4*)(pb + 4);
        }
        __syncthreads();
#pragma unroll
        for (int i = 0; i < 2; ++i) {
            const int chunk = i * 256 + tid;
            const int r = chunk >> 2, c = (chunk & 3) << 3;
            short8 sa, sb;
            sa[0]=(short)f2bf(ra[i][0].x); sa[1]=(short)f2bf(ra[i][0].y);
            sa[2]=(short)f2bf(ra[i][0].z); sa[3]=(short)f2bf(ra[i][0].w);
            sa[4]=(short)f2bf(ra[i][1].x); sa[5]=(short)f2bf(ra[i][1].y);
            sa[6]=(short)f2bf(ra[i][1].z); sa[7]=(short)f2bf(ra[i][1].w);
            sb[0]=(short)f2bf(rb[i][0].x); sb[1]=(short)f2bf(rb[i][0].y);
            sb[2]=(short)f2bf(rb[i][0].z); sb[3]=(short)f2bf(rb[i][0].w);
            sb[4]=(short)f2bf(rb[i][1].x); sb[5]=(short)f2bf(rb[i][1].y);
            sb[6]=(short)f2bf(rb[i][1].z); sb[7]=(short)f2bf(rb[i][1].w);
            *(short8*)&lA[r * 32 + c] = sa;
            *(short8*)&lB[r * 32 + c] = sb;
        }
        __syncthreads();
        short8 af[4], bf[4];
#pragma unroll
        for (int i = 0; i < 4; ++i)
            af[i] = *(const short8*)&lA[(waveM + i * 16 + fr) * 32 + fq * 8];
#pragma unroll
        for (int j = 0; j < 4; ++j)
            bf[j] = *(const short8*)&lB[(waveN + j * 16 + fr) * 32 + fq * 8];
#pragma unroll
        for (int i = 0; i < 4; ++i)
#pragma unroll
            for (int j = 0; j < 4; ++j)
                acc[i][j] = __builtin_amdgcn_mfma_f32_16x16x32_bf16(af[i], bf[j], acc[i][j], 0, 0, 0);
    }

    C += (long)blockIdx.z * sC;
#pragma unroll
    for (int j = 0; j < 4; ++j) {
        const int col = tileN + waveN + j * 16 + fr;
        const float bv = BIAS ? bias[col] : 0.0f;
#pragma unroll
        for (int i = 0; i < 4; ++i) {
            const int row0 = tileM + waveM + i * 16 + fq * 4;
#pragma unroll
            for (int r = 0; r < 4; ++r)
                C[(size_t)(row0 + r) * ldc + col] = f2bf(acc[i][j][r] + bv);
        }
    }
}

// ============ C = A * B^T, bf16 sources, bf16 out ============
__global__ __launch_bounds__(256, 2) void gemm_bt_b16(
    const u16* __restrict__ A, const u16* __restrict__ Bm,
    u16* __restrict__ C, int K, int ldc, long sA, long sB, long sC)
{
    __shared__ __align__(16) u16 lA[128 * 32];
    __shared__ __align__(16) u16 lB[128 * 32];
    const int tid = threadIdx.x;
    const int lane = tid & 63;
    const int fr = lane & 15, fq = lane >> 4;
    const int wv = tid >> 6;
    const int tileM = blockIdx.x * 128, tileN = blockIdx.y * 128;
    A  += (long)blockIdx.z * sA;
    Bm += (long)blockIdx.z * sB;

    floatx4 acc[4][4];
#pragma unroll
    for (int i = 0; i < 4; ++i)
#pragma unroll
        for (int j = 0; j < 4; ++j) acc[i][j] = (floatx4){0.f, 0.f, 0.f, 0.f};

    const int waveM = (wv >> 1) * 64, waveN = (wv & 1) * 64;

    for (int k0 = 0; k0 < K; k0 += 32) {
        short8 ra[2], rb[2];
#pragma unroll
        for (int i = 0; i < 2; ++i) {
            const int chunk = i * 256 + tid;
            const int r = chunk >> 2, c = (chunk & 3) << 3;
            ra[i] = *(const short8*)(A  + (size_t)(tileM + r) * K + (k0 + c));
            rb[i] = *(const short8*)(Bm + (size_t)(tileN + r) * K + (k0 + c));
        }
        __syncthreads();
#pragma unroll
        for (int i = 0; i < 2; ++i) {
            const int chunk = i * 256 + tid;
            const int r = chunk >> 2, c = (chunk & 3) << 3;
            *(short8*)&lA[r * 32 + c] = ra[i];
            *(short8*)&lB[r * 32 + c] = rb[i];
        }
        __syncthreads();
        short8 af[4], bf[4];
#pragma unroll
        for (int i = 0; i < 4; ++i)
            af[i] = *(const short8*)&lA[(waveM + i * 16 + fr) * 32 + fq * 8];
#pragma unroll
        for (int j = 0; j < 4; ++j)
            bf[j] = *(const short8*)&lB[(waveN + j * 16 + fr) * 32 + fq * 8];
#pragma unroll
        for (int i = 0; i < 4; ++i)
#pragma unroll
            for (int j = 0; j < 4; ++j)
                acc[i][j] = __builtin_amdgcn_mfma_f32_16x16x32_bf16(af[i], bf[j], acc[i][j], 0, 0, 0);
    }

    C += (long)blockIdx.z * sC;
#pragma unroll
    for (int j = 0; j < 4; ++j) {
        const int col = tileN + waveN + j * 16 + fr;
#pragma unroll
        for (int i = 0; i < 4; ++i) {
            const int row0 = tileM + waveM + i * 16 + fq * 4;
#pragma unroll
            for (int r = 0; r < 4; ++r)
                C[(size_t)(row0 + r) * ldc + col] = f2bf(acc[i][j][r]);
        }
    }
}

// ============ C = A * B (A: MxK rm bf16, B: KxN rm bf16), fp32 out ============
__global__ __launch_bounds__(256, 2) void gemm_nn(
    const u16* __restrict__ A, const u16* __restrict__ Bm, float* __restrict__ C,
    int K, int lda, int ldb, int ldc, long sA, long sB, long sC)
{
    __shared__ __align__(16) u16 lA[128 * 32];
    __shared__ __align__(16) u16 lBt[128 * 32];   // transposed: [n_local][k_local]
    const int tid = threadIdx.x;
    const int lane = tid & 63;
    const int fr = lane & 15, fq = lane >> 4;
    const int wv = tid >> 6;
    const int tileM = blockIdx.x * 128, tileN = blockIdx.y * 128;
    A  += (long)blockIdx.z * sA;
    Bm += (long)blockIdx.z * sB;

    floatx4 acc[4][4];
#pragma unroll
    for (int i = 0; i < 4; ++i)
#pragma unroll
        for (int j = 0; j < 4; ++j) acc[i][j] = (floatx4){0.f, 0.f, 0.f, 0.f};

    const int waveM = (wv >> 1) * 64, waveN = (wv & 1) * 64;

    for (int k0 = 0; k0 < K; k0 += 32) {
        short8 ra[2], rb[2];
#pragma unroll
        for (int i = 0; i < 2; ++i) {
            const int chunk = i * 256 + tid;
            const int r = chunk >> 2, c = (chunk & 3) << 3;
            ra[i] = *(const short8*)(A + (size_t)(tileM + r) * lda + (k0 + c));
        }
#pragma unroll
        for (int i = 0; i < 2; ++i) {
            const int chunk = i * 256 + tid;           // 512 chunks: 32(k) x 128(n)
            const int kr = chunk >> 4, nc = (chunk & 15) << 3;
            rb[i] = *(const short8*)(Bm + (size_t)(k0 + kr) * ldb + (tileN + nc));
        }
        __syncthreads();
#pragma unroll
        for (int i = 0; i < 2; ++i) {
            const int chunk = i * 256 + tid;
            const int r = chunk >> 2, c = (chunk & 3) << 3;
            *(short8*)&lA[r * 32 + c] = ra[i];
        }
#pragma unroll
        for (int i = 0; i < 2; ++i) {
            const int chunk = i * 256 + tid;
            const int kr = chunk >> 4, nc = (chunk & 15) << 3;
#pragma unroll
            for (int e = 0; e < 8; ++e) lBt[(nc + e) * 32 + kr] = (u16)rb[i][e];
        }
        __syncthreads();
        short8 af[4], bf[4];
#pragma unroll
        for (int i = 0; i < 4; ++i)
            af[i] = *(const short8*)&lA[(waveM + i * 16 + fr) * 32 + fq * 8];
#pragma unroll
        for (int j = 0; j < 4; ++j)
            bf[j] = *(const short8*)&lBt[(waveN + j * 16 + fr) * 32 + fq * 8];
#pragma unroll
        for (int i = 0; i < 4; ++i)
#pragma unroll
            for (int j = 0; j < 4; ++j)
                acc[i][j] = __builtin_amdgcn_mfma_f32_16x16x32_bf16(af[i], bf[j], acc[i][j], 0, 0, 0);
    }

    C += (long)blockIdx.z * sC;
#pragma unroll
    for (int j = 0; j < 4; ++j) {
        const int col = tileN + waveN + j * 16 + fr;
#pragma unroll
        for (int i = 0; i < 4; ++i) {
            const int row0 = tileM + waveM + i * 16 + fq * 4;
#pragma unroll
            for (int r = 0; r < 4; ++r)
                C[(size_t)(row0 + r) * ldc + col] = acc[i][j][r];
        }
    }
}

// ---------------- pooling: column means over axis 1 (fp32) ----------------
__global__ __launch_bounds__(256) void pool_kernel(
    const float* __restrict__ oV, const float* __restrict__ oT,
    float* __restrict__ vpool, float* __restrict__ tpool)
{
    const int col = blockIdx.x * 256 + threadIdx.x;
    const int b = blockIdx.y;
    const float* src = (blockIdx.z ? oT : oV) + (size_t)b * Mm * Dd;
    float s = 0.f;
    for (int r = 0; r < Mm; ++r) s += src[(size_t)r * Dd + col];
    float* dst = blockIdx.z ? tpool : vpool;
    dst[b * Dd + col] = s * (1.0f / Mm);
}

// ---------------- tiny FFN -> per-batch threshold l (fp32) ----------------
__global__ __launch_bounds__(256) void ffn_kernel(
    const float* __restrict__ vpool, const float* __restrict__ tpool,
    const float* __restrict__ f1w, const float* __restrict__ f1b,
    const float* __restrict__ f2w, const float* __restrict__ f2b,
    float* __restrict__ lbuf)
{
    const int b = blockIdx.x;
    __shared__ float xcat[2 * Dd];
    __shared__ float h[HIDh];
    __shared__ float red[4];
    const int t = threadIdx.x, wv = t >> 6, lane = t & 63;
    for (int i = t; i < Dd; i += 256) {
        xcat[i] = vpool[b * Dd + i];
        xcat[Dd + i] = tpool[b * Dd + i];
    }
    __syncthreads();
    for (int j = wv; j < HIDh; j += 4) {
        const float* wrow = f1w + (size_t)j * (2 * Dd);
        float a = 0.f;
        for (int k = lane; k < 2 * Dd; k += 64) a += xcat[k] * wrow[k];
        a = waveSum(a);
        if (lane == 0) h[j] = fmaxf(a + f1b[j], 0.0f);
    }
    __syncthreads();
    float p = 0.f;
    for (int j = t; j < HIDh; j += 256) p += h[j] * f2w[j];
    p = waveSum(p);
    if (lane == 0) red[wv] = p;
    __syncthreads();
    if (t == 0) {
        const float z = red[0] + red[1] + red[2] + red[3] + f2b[0];
        lbuf[b] = 1.0f / (1.0f + expf(-z));
    }
}

// ---------------- sim softmax (bf16 scores) -> fp32 mask (1.0/0.0) ----------------
__global__ __launch_bounds__(256) void sim_softmax_mask(
    const u16* __restrict__ scores, const float* __restrict__ lbuf, float* __restrict__ maskF)
{
    const int row = blockIdx.x, b = blockIdx.y;
    const int t = threadIdx.x, wv = t >> 6, lane = t & 63;
    __shared__ float red[8];
    const size_t off = ((size_t)b * Mm + row) * Nn;
    const uint2 sv = *(const uint2*)(scores + off + 4 * t);
    const float x0 = bf2f((u16)(sv.x & 0xFFFFu)) * INV_SQRT_D;
    const float x1 = bf2f((u16)(sv.x >> 16))     * INV_SQRT_D;
    const float x2 = bf2f((u16)(sv.y & 0xFFFFu)) * INV_SQRT_D;
    const float x3 = bf2f((u16)(sv.y >> 16))     * INV_SQRT_D;
    float mx = waveMax(fmaxf(fmaxf(x0, x1), fmaxf(x2, x3)));
    if (lane == 0) red[wv] = mx;
    __syncthreads();
    mx = fmaxf(fmaxf(red[0], red[1]), fmaxf(red[2], red[3]));
    const float e0 = expf(x0 - mx), e1 = expf(x1 - mx), e2 = expf(x2 - mx), e3 = expf(x3 - mx);
    float s = waveSum(e0 + e1 + e2 + e3);
    if (lane == 0) red[4 + wv] = s;
    __syncthreads();
    const float inv = 1.0f / fmaxf(red[4] + red[5] + red[6] + red[7], 1e-30f);
    const float l = lbuf[b];
    float4 mk;
    mk.x = (e0 * inv >= l) ? 1.0f : 0.0f;
    mk.y = (e1 * inv >= l) ? 1.0f : 0.0f;
    mk.z = (e2 * inv >= l) ? 1.0f : 0.0f;
    mk.w = (e3 * inv >= l) ? 1.0f : 0.0f;
    *(float4*)(maskF + off + 4 * t) = mk;
}

// ---------------- masked softmax over bf16 scores, IN-PLACE -> bf16 attn ----------------
// mask read as fp32 bit pattern (u32): nonzero == true.
template <bool TRANSP>
__global__ __launch_bounds__(256) void masked_softmax(
    u16* __restrict__ scores, const u32* __restrict__ mask32)
{
    const int row = blockIdx.x, b = blockIdx.y;
    const int t = threadIdx.x, wv = t >> 6, lane = t & 63;
    __shared__ float red[8];
    const size_t off = ((size_t)b * Mm + row) * Nn;
    const uint2 sv = *(const uint2*)(scores + off + 4 * t);
    float x0 = bf2f((u16)(sv.x & 0xFFFFu)) * INV_SQRT_D;
    float x1 = bf2f((u16)(sv.x >> 16))     * INV_SQRT_D;
    float x2 = bf2f((u16)(sv.y & 0xFFFFu)) * INV_SQRT_D;
    float x3 = bf2f((u16)(sv.y >> 16))     * INV_SQRT_D;
    if (TRANSP) {
        const u32* mcol = mask32 + (size_t)b * Mm * Nn + row;
        if (!mcol[(size_t)(4 * t + 0) * Nn]) x0 = NEGINF;
        if (!mcol[(size_t)(4 * t + 1) * Nn]) x1 = NEGINF;
        if (!mcol[(size_t)(4 * t + 2) * Nn]) x2 = NEGINF;
        if (!mcol[(size_t)(4 * t + 3) * Nn]) x3 = NEGINF;
    } else {
        const u32* mrow = mask32 + off + 4 * t;
        if (!mrow[0]) x0 = NEGINF;
        if (!mrow[1]) x1 = NEGINF;
        if (!mrow[2]) x2 = NEGINF;
        if (!mrow[3]) x3 = NEGINF;
    }
    float mx = waveMax(fmaxf(fmaxf(x0, x1), fmaxf(x2, x3)));
    if (lane == 0) red[wv] = mx;
    __syncthreads();
    mx = fmaxf(fmaxf(red[0], red[1]), fmaxf(red[2], red[3]));
    const float e0 = expf(x0 - mx), e1 = expf(x1 - mx), e2 = expf(x2 - mx), e3 = expf(x3 - mx);
    float s = waveSum(e0 + e1 + e2 + e3);
    if (lane == 0) red[4 + wv] = s;
    __syncthreads();
    const float inv = 1.0f / fmaxf(red[4] + red[5] + red[6] + red[7], 1e-30f);
    uint2 pk;
    pk.x = (u32)f2bf(e0 * inv) | ((u32)f2bf(e1 * inv) << 16);
    pk.y = (u32)f2bf(e2 * inv) | ((u32)f2bf(e3 * inv) << 16);
    *(uint2*)(scores + off + 4 * t) = pk;   // in-place: own 8 bytes only
}

extern "C" void kernel_launch(void* const* d_in, const int* in_sizes, int n_in,
                              void* d_out, int out_size, void* d_ws, size_t ws_size,
                              hipStream_t stream)
{
    (void)in_sizes; (void)n_in; (void)out_size; (void)ws_size;
    const float* oV     = (const float*)d_in[0];
    const float* oT     = (const float*)d_in[1];
    const float* Wq_v_w = (const float*)d_in[2];
    const float* Wq_v_b = (const float*)d_in[3];
    const float* Wk_t_w = (const float*)d_in[4];
    const float* Wk_t_b = (const float*)d_in[5];
    const float* Wv_t_w = (const float*)d_in[6];
    const float* Wv_t_b = (const float*)d_in[7];
    const float* Wq_t_w = (const float*)d_in[8];
    const float* Wq_t_b = (const float*)d_in[9];
    const float* Wk_v_w = (const float*)d_in[10];
    const float* Wk_v_b = (const float*)d_in[11];
    const float* Wv_v_w = (const float*)d_in[12];
    const float* Wv_v_b = (const float*)d_in[13];
    const float* f1w    = (const float*)d_in[14];
    const float* f1b    = (const float*)d_in[15];
    const float* f2w    = (const float*)d_in[16];
    const float* f2b    = (const float*)d_in[17];

    // d_out: fp32, three regions of BMD elements each
    float* out_vt = (float*)d_out;
    float* out_tv = out_vt + BMDc;
    float* maskF  = out_vt + 2 * BMDc;

    // ws: 3 bf16 projection slots + bf16 scores = 128 MB
    u16* U0 = (u16*)d_ws;
    u16* U1 = U0 + BMDc;
    u16* U2 = U1 + BMDc;
    u16* scoresB = U2 + BMDc;
    // pools/lbuf stash in out_vt region (dead before the first gemm_nn writes it)
    float* vpool = out_vt;
    float* tpool = vpool + Bz * Dd;
    float* lbuf  = tpool + Bz * Dd;

    const dim3 blk(256);
    const dim3 gBat(Mm / 128, Nn / 128, Bz);
    const dim3 gProj(Bz * Mm / 128, Dd / 128, 1);
    const dim3 gRow(Mm, Bz);
    const long sMD = (long)Mm * Dd, sMN = (long)Mm * Nn;

    // 1-2: pools + threshold l
    pool_kernel<<<dim3(Dd / 256, Bz, 2), blk, 0, stream>>>(oV, oT, vpool, tpool);
    ffn_kernel<<<dim3(Bz), blk, 0, stream>>>(vpool, tpool, f1w, f1b, f2w, f2b, lbuf);

    // 3-4: sim scores (bf16, ws) -> fp32 mask (d_out region 3)
    gemm_bt_f32<false><<<gBat, blk, 0, stream>>>(oV, oT, nullptr, scoresB, Dd, Nn, sMD, sMD, sMN);
    sim_softmax_mask<<<gRow, blk, 0, stream>>>(scoresB, lbuf, maskF);

    // 5-10: V->T.  Q_v->U0, K_t->U1, V_t->U2.
    gemm_bt_f32<true><<<gProj, blk, 0, stream>>>(oV, Wq_v_w, Wq_v_b, U0, Dd, Dd, 0, 0, 0);
    gemm_bt_f32<true><<<gProj, blk, 0, stream>>>(oT, Wk_t_w, Wk_t_b, U1, Dd, Dd, 0, 0, 0);
    gemm_bt_f32<true><<<gProj, blk, 0, stream>>>(oT, Wv_t_w, Wv_t_b, U2, Dd, Dd, 0, 0, 0);
    gemm_bt_b16<<<gBat, blk, 0, stream>>>(U0, U1, scoresB, Dd, Nn, sMD, sMD, sMN);
    masked_softmax<false><<<gRow, blk, 0, stream>>>(scoresB, (const u32*)maskF);
    gemm_nn<<<gBat, blk, 0, stream>>>(scoresB, U2, out_vt, Nn, Nn, Dd, Dd, sMN, sMD, sMD);

    // 11-16: T->V.  Q_t->U0, K_v->U1, V_v->U2.
    gemm_bt_f32<true><<<gProj, blk, 0, stream>>>(oT, Wq_t_w, Wq_t_b, U0, Dd, Dd, 0, 0, 0);
    gemm_bt_f32<true><<<gProj, blk, 0, stream>>>(oV, Wk_v_w, Wk_v_b, U1, Dd, Dd, 0, 0, 0);
    gemm_bt_f32<true><<<gProj, blk, 0, stream>>>(oV, Wv_v_w, Wv_v_b, U2, Dd, Dd, 0, 0, 0);
    gemm_bt_b16<<<gBat, blk, 0, stream>>>(U0, U1, scoresB, Dd, Nn, sMD, sMD, sMN);
    masked_softmax<true><<<gRow, blk, 0, stream>>>(scoresB, (const u32*)maskF);
    gemm_nn<<<gBat, blk, 0, stream>>>(scoresB, U2, out_tv, Nn, Nn, Dd, Dd, sMN, sMD, sMD);
}

// Round 5
// 1527.434 us; speedup vs baseline: 1.8997x; 1.8997x over previous
//
#include <hip/hip_runtime.h>
#include <stdint.h>

typedef unsigned short u16;
typedef unsigned int   u32;
typedef __attribute__((ext_vector_type(8))) short  short8;
typedef __attribute__((ext_vector_type(4))) float  floatx4;

#define Bz   16
#define Mm   1024
#define Nn   1024
#define Dd   1024
#define HIDh 512
#define INV_SQRT_D 0.03125f
#define NEGINF (-1.0e9f)
#define BMDc  ((size_t)Bz * Mm * Dd)

__device__ __forceinline__ float bf2f(u16 h) {
    union { u32 u; float f; } c; c.u = ((u32)h) << 16; return c.f;
}
__device__ __forceinline__ u16 f2bf(float f) {
    union { float f; u32 u; } c; c.f = f;
    u32 u = c.u;
    return (u16)((u + 0x7FFFu + ((u >> 16) & 1u)) >> 16);
}

__device__ __forceinline__ float waveSum(float v) {
#pragma unroll
    for (int o = 32; o > 0; o >>= 1) v += __shfl_xor(v, o);
    return v;
}
__device__ __forceinline__ float waveMax(float v) {
#pragma unroll
    for (int o = 32; o > 0; o >>= 1) v = fmaxf(v, __shfl_xor(v, o));
    return v;
}

// ============ C = A * B^T, fp32 sources converted to bf16 at staging, bf16 out ============
template <bool BIAS>
__global__ __launch_bounds__(256, 2) void gemm_bt_f32(
    const float* __restrict__ A, const float* __restrict__ Bm, const float* __restrict__ bias,
    u16* __restrict__ C, int K, int ldc, long sA, long sB, long sC)
{
    __shared__ __align__(16) u16 lA[128 * 32];
    __shared__ __align__(16) u16 lB[128 * 32];
    const int tid = threadIdx.x;
    const int lane = tid & 63;
    const int fr = lane & 15, fq = lane >> 4;
    const int wv = tid >> 6;
    const int tileM = blockIdx.x * 128, tileN = blockIdx.y * 128;
    A  += (long)blockIdx.z * sA;
    Bm += (long)blockIdx.z * sB;

    floatx4 acc[4][4];
#pragma unroll
    for (int i = 0; i < 4; ++i)
#pragma unroll
        for (int j = 0; j < 4; ++j) acc[i][j] = (floatx4){0.f, 0.f, 0.f, 0.f};

    const int waveM = (wv >> 1) * 64, waveN = (wv & 1) * 64;

    for (int k0 = 0; k0 < K; k0 += 32) {
        float4 ra[2][2], rb[2][2];
#pragma unroll
        for (int i = 0; i < 2; ++i) {
            const int chunk = i * 256 + tid;          // 8-elem chunk, row-major [128][32]
            const int r = chunk >> 2, c = (chunk & 3) << 3;
            const float* pa = A  + (size_t)(tileM + r) * K + (k0 + c);
            const float* pb = Bm + (size_t)(tileN + r) * K + (k0 + c);
            ra[i][0] = *(const float4*)pa; ra[i][1] = *(const float4*)(pa + 4);
            rb[i][0] = *(const float4*)pb; rb[i][1] = *(const float4*)(pb + 4);
        }
        __syncthreads();
#pragma unroll
        for (int i = 0; i < 2; ++i) {
            const int chunk = i * 256 + tid;
            const int r = chunk >> 2, c = (chunk & 3) << 3;
            short8 sa, sb;
            sa[0]=(short)f2bf(ra[i][0].x); sa[1]=(short)f2bf(ra[i][0].y);
            sa[2]=(short)f2bf(ra[i][0].z); sa[3]=(short)f2bf(ra[i][0].w);
            sa[4]=(short)f2bf(ra[i][1].x); sa[5]=(short)f2bf(ra[i][1].y);
            sa[6]=(short)f2bf(ra[i][1].z); sa[7]=(short)f2bf(ra[i][1].w);
            sb[0]=(short)f2bf(rb[i][0].x); sb[1]=(short)f2bf(rb[i][0].y);
            sb[2]=(short)f2bf(rb[i][0].z); sb[3]=(short)f2bf(rb[i][0].w);
            sb[4]=(short)f2bf(rb[i][1].x); sb[5]=(short)f2bf(rb[i][1].y);
            sb[6]=(short)f2bf(rb[i][1].z); sb[7]=(short)f2bf(rb[i][1].w);
            *(short8*)&lA[r * 32 + c] = sa;
            *(short8*)&lB[r * 32 + c] = sb;
        }
        __syncthreads();
        short8 af[4], bf[4];
#pragma unroll
        for (int i = 0; i < 4; ++i)
            af[i] = *(const short8*)&lA[(waveM + i * 16 + fr) * 32 + fq * 8];
#pragma unroll
        for (int j = 0; j < 4; ++j)
            bf[j] = *(const short8*)&lB[(waveN + j * 16 + fr) * 32 + fq * 8];
#pragma unroll
        for (int i = 0; i < 4; ++i)
#pragma unroll
            for (int j = 0; j < 4; ++j)
                acc[i][j] = __builtin_amdgcn_mfma_f32_16x16x32_bf16(af[i], bf[j], acc[i][j], 0, 0, 0);
    }

    C += (long)blockIdx.z * sC;
#pragma unroll
    for (int j = 0; j < 4; ++j) {
        const int col = tileN + waveN + j * 16 + fr;
        const float bv = BIAS ? bias[col] : 0.0f;
#pragma unroll
        for (int i = 0; i < 4; ++i) {
            const int row0 = tileM + waveM + i * 16 + fq * 4;
#pragma unroll
            for (int r = 0; r < 4; ++r)
                C[(size_t)(row0 + r) * ldc + col] = f2bf(acc[i][j][r] + bv);
        }
    }
}

// ============ C = A * B^T, bf16 sources, bf16 out ============
__global__ __launch_bounds__(256, 2) void gemm_bt_b16(
    const u16* __restrict__ A, const u16* __restrict__ Bm,
    u16* __restrict__ C, int K, int ldc, long sA, long sB, long sC)
{
    __shared__ __align__(16) u16 lA[128 * 32];
    __shared__ __align__(16) u16 lB[128 * 32];
    const int tid = threadIdx.x;
    const int lane = tid & 63;
    const int fr = lane & 15, fq = lane >> 4;
    const int wv = tid >> 6;
    const int tileM = blockIdx.x * 128, tileN = blockIdx.y * 128;
    A  += (long)blockIdx.z * sA;
    Bm += (long)blockIdx.z * sB;

    floatx4 acc[4][4];
#pragma unroll
    for (int i = 0; i < 4; ++i)
#pragma unroll
        for (int j = 0; j < 4; ++j) acc[i][j] = (floatx4){0.f, 0.f, 0.f, 0.f};

    const int waveM = (wv >> 1) * 64, waveN = (wv & 1) * 64;

    for (int k0 = 0; k0 < K; k0 += 32) {
        short8 ra[2], rb[2];
#pragma unroll
        for (int i = 0; i < 2; ++i) {
            const int chunk = i * 256 + tid;
            const int r = chunk >> 2, c = (chunk & 3) << 3;
            ra[i] = *(const short8*)(A  + (size_t)(tileM + r) * K + (k0 + c));
            rb[i] = *(const short8*)(Bm + (size_t)(tileN + r) * K + (k0 + c));
        }
        __syncthreads();
#pragma unroll
        for (int i = 0; i < 2; ++i) {
            const int chunk = i * 256 + tid;
            const int r = chunk >> 2, c = (chunk & 3) << 3;
            *(short8*)&lA[r * 32 + c] = ra[i];
            *(short8*)&lB[r * 32 + c] = rb[i];
        }
        __syncthreads();
        short8 af[4], bf[4];
#pragma unroll
        for (int i = 0; i < 4; ++i)
            af[i] = *(const short8*)&lA[(waveM + i * 16 + fr) * 32 + fq * 8];
#pragma unroll
        for (int j = 0; j < 4; ++j)
            bf[j] = *(const short8*)&lB[(waveN + j * 16 + fr) * 32 + fq * 8];
#pragma unroll
        for (int i = 0; i < 4; ++i)
#pragma unroll
            for (int j = 0; j < 4; ++j)
                acc[i][j] = __builtin_amdgcn_mfma_f32_16x16x32_bf16(af[i], bf[j], acc[i][j], 0, 0, 0);
    }

    C += (long)blockIdx.z * sC;
#pragma unroll
    for (int j = 0; j < 4; ++j) {
        const int col = tileN + waveN + j * 16 + fr;
#pragma unroll
        for (int i = 0; i < 4; ++i) {
            const int row0 = tileM + waveM + i * 16 + fq * 4;
#pragma unroll
            for (int r = 0; r < 4; ++r)
                C[(size_t)(row0 + r) * ldc + col] = f2bf(acc[i][j][r]);
        }
    }
}

// ============ C = A * B (A: MxK rm bf16, B: KxN rm bf16), fp32 out ============
__global__ __launch_bounds__(256, 2) void gemm_nn(
    const u16* __restrict__ A, const u16* __restrict__ Bm, float* __restrict__ C,
    int K, int lda, int ldb, int ldc, long sA, long sB, long sC)
{
    __shared__ __align__(16) u16 lA[128 * 32];
    __shared__ __align__(16) u16 lBt[128 * 32];   // transposed: [n_local][k_local]
    const int tid = threadIdx.x;
    const int lane = tid & 63;
    const int fr = lane & 15, fq = lane >> 4;
    const int wv = tid >> 6;
    const int tileM = blockIdx.x * 128, tileN = blockIdx.y * 128;
    A  += (long)blockIdx.z * sA;
    Bm += (long)blockIdx.z * sB;

    floatx4 acc[4][4];
#pragma unroll
    for (int i = 0; i < 4; ++i)
#pragma unroll
        for (int j = 0; j < 4; ++j) acc[i][j] = (floatx4){0.f, 0.f, 0.f, 0.f};

    const int waveM = (wv >> 1) * 64, waveN = (wv & 1) * 64;

    for (int k0 = 0; k0 < K; k0 += 32) {
        short8 ra[2], rb[2];
#pragma unroll
        for (int i = 0; i < 2; ++i) {
            const int chunk = i * 256 + tid;
            const int r = chunk >> 2, c = (chunk & 3) << 3;
            ra[i] = *(const short8*)(A + (size_t)(tileM + r) * lda + (k0 + c));
        }
#pragma unroll
        for (int i = 0; i < 2; ++i) {
            const int chunk = i * 256 + tid;           // 512 chunks: 32(k) x 128(n)
            const int kr = chunk >> 4, nc = (chunk & 15) << 3;
            rb[i] = *(const short8*)(Bm + (size_t)(k0 + kr) * ldb + (tileN + nc));
        }
        __syncthreads();
#pragma unroll
        for (int i = 0; i < 2; ++i) {
            const int chunk = i * 256 + tid;
            const int r = chunk >> 2, c = (chunk & 3) << 3;
            *(short8*)&lA[r * 32 + c] = ra[i];
        }
#pragma unroll
        for (int i = 0; i < 2; ++i) {
            const int chunk = i * 256 + tid;
            const int kr = chunk >> 4, nc = (chunk & 15) << 3;
#pragma unroll
            for (int e = 0; e < 8; ++e) lBt[(nc + e) * 32 + kr] = (u16)rb[i][e];
        }
        __syncthreads();
        short8 af[4], bf[4];
#pragma unroll
        for (int i = 0; i < 4; ++i)
            af[i] = *(const short8*)&lA[(waveM + i * 16 + fr) * 32 + fq * 8];
#pragma unroll
        for (int j = 0; j < 4; ++j)
            bf[j] = *(const short8*)&lBt[(waveN + j * 16 + fr) * 32 + fq * 8];
#pragma unroll
        for (int i = 0; i < 4; ++i)
#pragma unroll
            for (int j = 0; j < 4; ++j)
                acc[i][j] = __builtin_amdgcn_mfma_f32_16x16x32_bf16(af[i], bf[j], acc[i][j], 0, 0, 0);
    }

    C += (long)blockIdx.z * sC;
#pragma unroll
    for (int j = 0; j < 4; ++j) {
        const int col = tileN + waveN + j * 16 + fr;
#pragma unroll
        for (int i = 0; i < 4; ++i) {
            const int row0 = tileM + waveM + i * 16 + fq * 4;
#pragma unroll
            for (int r = 0; r < 4; ++r)
                C[(size_t)(row0 + r) * ldc + col] = acc[i][j][r];
        }
    }
}

// ---------------- pooling: column means, row-chunked + atomics ----------------
// grid (Dd/256, Bz, 8): z = src*4 + row-chunk; 512 blocks total.
__global__ __launch_bounds__(256) void pool_kernel(
    const float* __restrict__ oV, const float* __restrict__ oT,
    float* __restrict__ vpool, float* __restrict__ tpool)
{
    const int col = blockIdx.x * 256 + threadIdx.x;
    const int b = blockIdx.y;
    const int src_i = blockIdx.z & 1, chunk = blockIdx.z >> 1;
    const float* src = (src_i ? oT : oV) + (size_t)b * Mm * Dd;
    const int r0 = chunk * (Mm / 4);
    float s = 0.f;
    for (int r = r0; r < r0 + Mm / 4; ++r) s += src[(size_t)r * Dd + col];
    float* dst = src_i ? tpool : vpool;
    atomicAdd(dst + b * Dd + col, s * (1.0f / Mm));
}

// ---------------- FFN stage 1: h[b][j] = relu(xcat_b . f1w[j] + f1b[j]) ----------------
// grid (HIDh, Bz) = 8192 blocks.
__global__ __launch_bounds__(256) void ffn1_kernel(
    const float* __restrict__ vpool, const float* __restrict__ tpool,
    const float* __restrict__ f1w, const float* __restrict__ f1b,
    float* __restrict__ hbuf)
{
    const int j = blockIdx.x, b = blockIdx.y;
    const int t = threadIdx.x, wv = t >> 6, lane = t & 63;
    __shared__ float red[4];
    const float* w = f1w + (size_t)j * (2 * Dd);
    float a = 0.f;
    for (int k = t; k < Dd; k += 256) a += vpool[b * Dd + k] * w[k];
    for (int k = t; k < Dd; k += 256) a += tpool[b * Dd + k] * w[Dd + k];
    a = waveSum(a);
    if (lane == 0) red[wv] = a;
    __syncthreads();
    if (t == 0) hbuf[b * HIDh + j] = fmaxf(red[0] + red[1] + red[2] + red[3] + f1b[j], 0.0f);
}

// ---------------- FFN stage 2: l[b] = sigmoid(h_b . f2w + f2b) ----------------
__global__ __launch_bounds__(256) void ffn2_kernel(
    const float* __restrict__ hbuf, const float* __restrict__ f2w,
    const float* __restrict__ f2b, float* __restrict__ lbuf)
{
    const int b = blockIdx.x;
    const int t = threadIdx.x, wv = t >> 6, lane = t & 63;
    __shared__ float red[4];
    float p = 0.f;
    for (int j = t; j < HIDh; j += 256) p += hbuf[b * HIDh + j] * f2w[j];
    p = waveSum(p);
    if (lane == 0) red[wv] = p;
    __syncthreads();
    if (t == 0) {
        const float z = red[0] + red[1] + red[2] + red[3] + f2b[0];
        lbuf[b] = 1.0f / (1.0f + expf(-z));
    }
}

// ---------------- sim softmax (bf16 scores) -> fp32 mask (1.0/0.0) ----------------
__global__ __launch_bounds__(256) void sim_softmax_mask(
    const u16* __restrict__ scores, const float* __restrict__ lbuf, float* __restrict__ maskF)
{
    const int row = blockIdx.x, b = blockIdx.y;
    const int t = threadIdx.x, wv = t >> 6, lane = t & 63;
    __shared__ float red[8];
    const size_t off = ((size_t)b * Mm + row) * Nn;
    const uint2 sv = *(const uint2*)(scores + off + 4 * t);
    const float x0 = bf2f((u16)(sv.x & 0xFFFFu)) * INV_SQRT_D;
    const float x1 = bf2f((u16)(sv.x >> 16))     * INV_SQRT_D;
    const float x2 = bf2f((u16)(sv.y & 0xFFFFu)) * INV_SQRT_D;
    const float x3 = bf2f((u16)(sv.y >> 16))     * INV_SQRT_D;
    float mx = waveMax(fmaxf(fmaxf(x0, x1), fmaxf(x2, x3)));
    if (lane == 0) red[wv] = mx;
    __syncthreads();
    mx = fmaxf(fmaxf(red[0], red[1]), fmaxf(red[2], red[3]));
    const float e0 = expf(x0 - mx), e1 = expf(x1 - mx), e2 = expf(x2 - mx), e3 = expf(x3 - mx);
    float s = waveSum(e0 + e1 + e2 + e3);
    if (lane == 0) red[4 + wv] = s;
    __syncthreads();
    const float inv = 1.0f / fmaxf(red[4] + red[5] + red[6] + red[7], 1e-30f);
    const float l = lbuf[b];
    float4 mk;
    mk.x = (e0 * inv >= l) ? 1.0f : 0.0f;
    mk.y = (e1 * inv >= l) ? 1.0f : 0.0f;
    mk.z = (e2 * inv >= l) ? 1.0f : 0.0f;
    mk.w = (e3 * inv >= l) ? 1.0f : 0.0f;
    *(float4*)(maskF + off + 4 * t) = mk;
}

// ---------------- masked softmax over bf16 scores, IN-PLACE -> bf16 attn ----------------
template <bool TRANSP>
__global__ __launch_bounds__(256) void masked_softmax(
    u16* __restrict__ scores, const u32* __restrict__ mask32)
{
    const int row = blockIdx.x, b = blockIdx.y;
    const int t = threadIdx.x, wv = t >> 6, lane = t & 63;
    __shared__ float red[8];
    const size_t off = ((size_t)b * Mm + row) * Nn;
    const uint2 sv = *(const uint2*)(scores + off + 4 * t);
    float x0 = bf2f((u16)(sv.x & 0xFFFFu)) * INV_SQRT_D;
    float x1 = bf2f((u16)(sv.x >> 16))     * INV_SQRT_D;
    float x2 = bf2f((u16)(sv.y & 0xFFFFu)) * INV_SQRT_D;
    float x3 = bf2f((u16)(sv.y >> 16))     * INV_SQRT_D;
    if (TRANSP) {
        const u32* mcol = mask32 + (size_t)b * Mm * Nn + row;
        if (!mcol[(size_t)(4 * t + 0) * Nn]) x0 = NEGINF;
        if (!mcol[(size_t)(4 * t + 1) * Nn]) x1 = NEGINF;
        if (!mcol[(size_t)(4 * t + 2) * Nn]) x2 = NEGINF;
        if (!mcol[(size_t)(4 * t + 3) * Nn]) x3 = NEGINF;
    } else {
        const u32* mrow = mask32 + off + 4 * t;
        if (!mrow[0]) x0 = NEGINF;
        if (!mrow[1]) x1 = NEGINF;
        if (!mrow[2]) x2 = NEGINF;
        if (!mrow[3]) x3 = NEGINF;
    }
    float mx = waveMax(fmaxf(fmaxf(x0, x1), fmaxf(x2, x3)));
    if (lane == 0) red[wv] = mx;
    __syncthreads();
    mx = fmaxf(fmaxf(red[0], red[1]), fmaxf(red[2], red[3]));
    const float e0 = expf(x0 - mx), e1 = expf(x1 - mx), e2 = expf(x2 - mx), e3 = expf(x3 - mx);
    float s = waveSum(e0 + e1 + e2 + e3);
    if (lane == 0) red[4 + wv] = s;
    __syncthreads();
    const float inv = 1.0f / fmaxf(red[4] + red[5] + red[6] + red[7], 1e-30f);
    uint2 pk;
    pk.x = (u32)f2bf(e0 * inv) | ((u32)f2bf(e1 * inv) << 16);
    pk.y = (u32)f2bf(e2 * inv) | ((u32)f2bf(e3 * inv) << 16);
    *(uint2*)(scores + off + 4 * t) = pk;   // in-place: own 8 bytes only
}

extern "C" void kernel_launch(void* const* d_in, const int* in_sizes, int n_in,
                              void* d_out, int out_size, void* d_ws, size_t ws_size,
                              hipStream_t stream)
{
    (void)in_sizes; (void)n_in; (void)out_size; (void)ws_size;
    const float* oV     = (const float*)d_in[0];
    const float* oT     = (const float*)d_in[1];
    const float* Wq_v_w = (const float*)d_in[2];
    const float* Wq_v_b = (const float*)d_in[3];
    const float* Wk_t_w = (const float*)d_in[4];
    const float* Wk_t_b = (const float*)d_in[5];
    const float* Wv_t_w = (const float*)d_in[6];
    const float* Wv_t_b = (const float*)d_in[7];
    const float* Wq_t_w = (const float*)d_in[8];
    const float* Wq_t_b = (const float*)d_in[9];
    const float* Wk_v_w = (const float*)d_in[10];
    const float* Wk_v_b = (const float*)d_in[11];
    const float* Wv_v_w = (const float*)d_in[12];
    const float* Wv_v_b = (const float*)d_in[13];
    const float* f1w    = (const float*)d_in[14];
    const float* f1b    = (const float*)d_in[15];
    const float* f2w    = (const float*)d_in[16];
    const float* f2b    = (const float*)d_in[17];

    // d_out: fp32, three regions of BMD elements each
    float* out_vt = (float*)d_out;
    float* out_tv = out_vt + BMDc;
    float* maskF  = out_vt + 2 * BMDc;

    // ws: 3 bf16 projection slots + bf16 scores = 128 MB
    u16* U0 = (u16*)d_ws;
    u16* U1 = U0 + BMDc;
    u16* U2 = U1 + BMDc;
    u16* scoresB = U2 + BMDc;
    // small scratch stashed in out_vt region (dead until the first gemm_nn at step 10)
    float* vpool = out_vt;                  // Bz*Dd
    float* tpool = vpool + Bz * Dd;         // Bz*Dd
    float* hbuf  = tpool + Bz * Dd;         // Bz*HIDh
    float* lbuf  = hbuf + Bz * HIDh;        // Bz

    const dim3 blk(256);
    const dim3 gBat(Mm / 128, Nn / 128, Bz);
    const dim3 gProj(Bz * Mm / 128, Dd / 128, 1);
    const dim3 gRow(Mm, Bz);
    const long sMD = (long)Mm * Dd, sMN = (long)Mm * Nn;

    // 1-2: pools (atomic partials; zero-init) + threshold l
    hipMemsetAsync(vpool, 0, 2 * Bz * Dd * sizeof(float), stream);
    pool_kernel<<<dim3(Dd / 256, Bz, 8), blk, 0, stream>>>(oV, oT, vpool, tpool);
    ffn1_kernel<<<dim3(HIDh, Bz), blk, 0, stream>>>(vpool, tpool, f1w, f1b, hbuf);
    ffn2_kernel<<<dim3(Bz), blk, 0, stream>>>(hbuf, f2w, f2b, lbuf);

    // 3-4: sim scores (bf16, ws) -> fp32 mask (d_out region 3)
    gemm_bt_f32<false><<<gBat, blk, 0, stream>>>(oV, oT, nullptr, scoresB, Dd, Nn, sMD, sMD, sMN);
    sim_softmax_mask<<<gRow, blk, 0, stream>>>(scoresB, lbuf, maskF);

    // 5-10: V->T.  Q_v->U0, K_t->U1, V_t->U2.
    gemm_bt_f32<true><<<gProj, blk, 0, stream>>>(oV, Wq_v_w, Wq_v_b, U0, Dd, Dd, 0, 0, 0);
    gemm_bt_f32<true><<<gProj, blk, 0, stream>>>(oT, Wk_t_w, Wk_t_b, U1, Dd, Dd, 0, 0, 0);
    gemm_bt_f32<true><<<gProj, blk, 0, stream>>>(oT, Wv_t_w, Wv_t_b, U2, Dd, Dd, 0, 0, 0);
    gemm_bt_b16<<<gBat, blk, 0, stream>>>(U0, U1, scoresB, Dd, Nn, sMD, sMD, sMN);
    masked_softmax<false><<<gRow, blk, 0, stream>>>(scoresB, (const u32*)maskF);
    gemm_nn<<<gBat, blk, 0, stream>>>(scoresB, U2, out_vt, Nn, Nn, Dd, Dd, sMN, sMD, sMD);

    // 11-16: T->V.  Q_t->U0, K_v->U1, V_v->U2.
    gemm_bt_f32<true><<<gProj, blk, 0, stream>>>(oT, Wq_t_w, Wq_t_b, U0, Dd, Dd, 0, 0, 0);
    gemm_bt_f32<true><<<gProj, blk, 0, stream>>>(oV, Wk_v_w, Wk_v_b, U1, Dd, Dd, 0, 0, 0);
    gemm_bt_f32<true><<<gProj, blk, 0, stream>>>(oV, Wv_v_w, Wv_v_b, U2, Dd, Dd, 0, 0, 0);
    gemm_bt_b16<<<gBat, blk, 0, stream>>>(U0, U1, scoresB, Dd, Nn, sMD, sMD, sMN);
    masked_softmax<true><<<gRow, blk, 0, stream>>>(scoresB, (const u32*)maskF);
    gemm_nn<<<gBat, blk, 0, stream>>>(scoresB, U2, out_tv, Nn, Nn, Dd, Dd, sMN, sMD, sMD);
}

// Round 6
// 1180.370 us; speedup vs baseline: 2.4583x; 1.2940x over previous
//
#include <hip/hip_runtime.h>
#include <stdint.h>

typedef unsigned short u16;
typedef unsigned int   u32;
typedef __attribute__((ext_vector_type(8))) short  short8;
typedef __attribute__((ext_vector_type(4))) float  floatx4;

#define Bz   16
#define Mm   1024
#define Nn   1024
#define Dd   1024
#define HIDh 512
#define INV_SQRT_D 0.03125f
#define NEGINF (-1.0e9f)
#define BMDc  ((size_t)Bz * Mm * Dd)
#define sMDc  ((long)Mm * Dd)

__device__ __forceinline__ float bf2f(u16 h) {
    union { u32 u; float f; } c; c.u = ((u32)h) << 16; return c.f;
}
__device__ __forceinline__ u16 f2bf(float f) {
    union { float f; u32 u; } c; c.f = f;
    u32 u = c.u;
    return (u16)((u + 0x7FFFu + ((u >> 16) & 1u)) >> 16);
}
// async global->LDS, 16B/lane; lds ptr must be wave-uniform (HW adds lane*16)
__device__ __forceinline__ void g2lds16(const u16* g, u16* l) {
    __builtin_amdgcn_global_load_lds((const __attribute__((address_space(1))) void*)g,
                                     (__attribute__((address_space(3))) void*)l, 16, 0, 0);
}

__device__ __forceinline__ float waveSum(float v) {
#pragma unroll
    for (int o = 32; o > 0; o >>= 1) v += __shfl_xor(v, o);
    return v;
}
__device__ __forceinline__ float waveMax(float v) {
#pragma unroll
    for (int o = 32; o > 0; o >>= 1) v = fmaxf(v, __shfl_xor(v, o));
    return v;
}

// ============ C = A * B^T, bf16 A/B via async LDS staging (m97 recipe) ============
// OUT_FP32=false: bf16 C.  OUT_FP32=true: fp32 C.
template <bool OUT_FP32>
__global__ __launch_bounds__(256, 2) void gemm_bt_async(
    const u16* __restrict__ A, const u16* __restrict__ Bm,
    void* __restrict__ Cv, int K, int ldc, long sA, long sB, long sC)
{
    __shared__ __align__(16) u16 lA[128 * 32];
    __shared__ __align__(16) u16 lB[128 * 32];
    const int tid = threadIdx.x;
    const int lane = tid & 63;
    const int fr = lane & 15, fq = lane >> 4;
    const int wv = tid >> 6;
    const int tileM = blockIdx.x * 128, tileN = blockIdx.y * 128;
    A  += (long)blockIdx.z * sA;
    Bm += (long)blockIdx.z * sB;

    floatx4 acc[4][4];
#pragma unroll
    for (int i = 0; i < 4; ++i)
#pragma unroll
        for (int j = 0; j < 4; ++j) acc[i][j] = (floatx4){0.f, 0.f, 0.f, 0.f};

    const int waveM = (wv >> 1) * 64, waveN = (wv & 1) * 64;

    for (int k0 = 0; k0 < K; k0 += 32) {
        __syncthreads();                       // readers of previous tile done
#pragma unroll
        for (int i = 0; i < 2; ++i) {
            const int chunk = i * 256 + tid;   // 16B chunk id, row-major [128][32]
            const int r = chunk >> 2, c = (chunk & 3) << 3;
            const int wbase = (i * 256 + wv * 64) * 8;   // wave-uniform LDS base (u16 idx)
            g2lds16(A  + (size_t)(tileM + r) * K + (k0 + c), &lA[wbase]);
            g2lds16(Bm + (size_t)(tileN + r) * K + (k0 + c), &lB[wbase]);
        }
        __syncthreads();                       // drains vmcnt -> LDS visible
        short8 af[4], bf[4];
#pragma unroll
        for (int i = 0; i < 4; ++i)
            af[i] = *(const short8*)&lA[(waveM + i * 16 + fr) * 32 + fq * 8];
#pragma unroll
        for (int j = 0; j < 4; ++j)
            bf[j] = *(const short8*)&lB[(waveN + j * 16 + fr) * 32 + fq * 8];
#pragma unroll
        for (int i = 0; i < 4; ++i)
#pragma unroll
            for (int j = 0; j < 4; ++j)
                acc[i][j] = __builtin_amdgcn_mfma_f32_16x16x32_bf16(af[i], bf[j], acc[i][j], 0, 0, 0);
    }

    if (OUT_FP32) {
        float* C = (float*)Cv + (long)blockIdx.z * sC;
#pragma unroll
        for (int j = 0; j < 4; ++j) {
            const int col = tileN + waveN + j * 16 + fr;
#pragma unroll
            for (int i = 0; i < 4; ++i) {
                const int row0 = tileM + waveM + i * 16 + fq * 4;
#pragma unroll
                for (int r = 0; r < 4; ++r)
                    C[(size_t)(row0 + r) * ldc + col] = acc[i][j][r];
            }
        }
    } else {
        u16* C = (u16*)Cv + (long)blockIdx.z * sC;
#pragma unroll
        for (int j = 0; j < 4; ++j) {
            const int col = tileN + waveN + j * 16 + fr;
#pragma unroll
            for (int i = 0; i < 4; ++i) {
                const int row0 = tileM + waveM + i * 16 + fq * 4;
#pragma unroll
                for (int r = 0; r < 4; ++r)
                    C[(size_t)(row0 + r) * ldc + col] = f2bf(acc[i][j][r]);
            }
        }
    }
}

// ============ Projection: C = A * W^T + bias.  A bf16 (async), W fp32 (reg-convert) ============
// A: (Bz*Mm) x K bf16 row-major.  W: Dd x K fp32 row-major.  bias fp32.
// TRANSC=false: C[row][col] bf16 (ld=Dd, batched implicitly by row).
// TRANSC=true : C stored per-batch transposed: C[b][col][m] (V^T layout for the PV GEMM).
template <bool TRANSC>
__global__ __launch_bounds__(256, 2) void gemm_proj(
    const u16* __restrict__ A, const float* __restrict__ Wf, const float* __restrict__ bias,
    u16* __restrict__ C, int K)
{
    __shared__ __align__(16) u16 lA[128 * 32];
    __shared__ __align__(16) u16 lB[128 * 32];
    const int tid = threadIdx.x;
    const int lane = tid & 63;
    const int fr = lane & 15, fq = lane >> 4;
    const int wv = tid >> 6;
    const int tileM = blockIdx.x * 128, tileN = blockIdx.y * 128;

    floatx4 acc[4][4];
#pragma unroll
    for (int i = 0; i < 4; ++i)
#pragma unroll
        for (int j = 0; j < 4; ++j) acc[i][j] = (floatx4){0.f, 0.f, 0.f, 0.f};

    const int waveM = (wv >> 1) * 64, waveN = (wv & 1) * 64;

    for (int k0 = 0; k0 < K; k0 += 32) {
        float4 rb[2][2];
#pragma unroll
        for (int i = 0; i < 2; ++i) {          // W tile 128x32 fp32 -> regs (pre-barrier)
            const int chunk = i * 256 + tid;
            const int r = chunk >> 2, c = (chunk & 3) << 3;
            const float* p = Wf + (size_t)(tileN + r) * K + (k0 + c);
            rb[i][0] = *(const float4*)p; rb[i][1] = *(const float4*)(p + 4);
        }
        __syncthreads();
#pragma unroll
        for (int i = 0; i < 2; ++i) {          // A tile async
            const int chunk = i * 256 + tid;
            const int r = chunk >> 2, c = (chunk & 3) << 3;
            const int wbase = (i * 256 + wv * 64) * 8;
            g2lds16(A + (size_t)(tileM + r) * K + (k0 + c), &lA[wbase]);
            (void)r; (void)c;
        }
#pragma unroll
        for (int i = 0; i < 2; ++i) {          // W tile convert -> LDS
            const int chunk = i * 256 + tid;
            const int r = chunk >> 2, c = (chunk & 3) << 3;
            short8 sb;
            sb[0]=(short)f2bf(rb[i][0].x); sb[1]=(short)f2bf(rb[i][0].y);
            sb[2]=(short)f2bf(rb[i][0].z); sb[3]=(short)f2bf(rb[i][0].w);
            sb[4]=(short)f2bf(rb[i][1].x); sb[5]=(short)f2bf(rb[i][1].y);
            sb[6]=(short)f2bf(rb[i][1].z); sb[7]=(short)f2bf(rb[i][1].w);
            *(short8*)&lB[r * 32 + c] = sb;
        }
        __syncthreads();
        short8 af[4], bf[4];
#pragma unroll
        for (int i = 0; i < 4; ++i)
            af[i] = *(const short8*)&lA[(waveM + i * 16 + fr) * 32 + fq * 8];
#pragma unroll
        for (int j = 0; j < 4; ++j)
            bf[j] = *(const short8*)&lB[(waveN + j * 16 + fr) * 32 + fq * 8];
#pragma unroll
        for (int i = 0; i < 4; ++i)
#pragma unroll
            for (int j = 0; j < 4; ++j)
                acc[i][j] = __builtin_amdgcn_mfma_f32_16x16x32_bf16(af[i], bf[j], acc[i][j], 0, 0, 0);
    }

#pragma unroll
    for (int j = 0; j < 4; ++j) {
        const int col = tileN + waveN + j * 16 + fr;
        const float bv = bias[col];
#pragma unroll
        for (int i = 0; i < 4; ++i) {
            const int row0 = tileM + waveM + i * 16 + fq * 4;
#pragma unroll
            for (int r = 0; r < 4; ++r) {
                const int row = row0 + r;
                if (TRANSC) {
                    const int b = row >> 10, mloc = row & 1023;
                    C[(size_t)b * sMDc + (size_t)col * Mm + mloc] = f2bf(acc[i][j][r] + bv);
                } else {
                    C[(size_t)row * Dd + col] = f2bf(acc[i][j][r] + bv);
                }
            }
        }
    }
}

// ---------------- fp32 -> bf16 conversion (vectorized, grid-stride) ----------------
__global__ __launch_bounds__(256) void conv_kernel(
    const float* __restrict__ src, u16* __restrict__ dst, size_t n8)
{
    const size_t stride = (size_t)gridDim.x * 256;
    for (size_t i = (size_t)blockIdx.x * 256 + threadIdx.x; i < n8; i += stride) {
        const float4 a = ((const float4*)src)[2 * i];
        const float4 b = ((const float4*)src)[2 * i + 1];
        short8 o;
        o[0]=(short)f2bf(a.x); o[1]=(short)f2bf(a.y); o[2]=(short)f2bf(a.z); o[3]=(short)f2bf(a.w);
        o[4]=(short)f2bf(b.x); o[5]=(short)f2bf(b.y); o[6]=(short)f2bf(b.z); o[7]=(short)f2bf(b.w);
        *(short8*)(dst + 8 * i) = o;
    }
}

// ---------------- pooling: column means, row-chunked + atomics ----------------
__global__ __launch_bounds__(256) void pool_kernel(
    const float* __restrict__ oV, const float* __restrict__ oT,
    float* __restrict__ vpool, float* __restrict__ tpool)
{
    const int col = blockIdx.x * 256 + threadIdx.x;
    const int b = blockIdx.y;
    const int src_i = blockIdx.z & 1, chunk = blockIdx.z >> 1;
    const float* src = (src_i ? oT : oV) + (size_t)b * Mm * Dd;
    const int r0 = chunk * (Mm / 4);
    float s = 0.f;
    for (int r = r0; r < r0 + Mm / 4; ++r) s += src[(size_t)r * Dd + col];
    float* dst = src_i ? tpool : vpool;
    atomicAdd(dst + b * Dd + col, s * (1.0f / Mm));
}

// ---------------- FFN stage 1 ----------------
__global__ __launch_bounds__(256) void ffn1_kernel(
    const float* __restrict__ vpool, const float* __restrict__ tpool,
    const float* __restrict__ f1w, const float* __restrict__ f1b,
    float* __restrict__ hbuf)
{
    const int j = blockIdx.x, b = blockIdx.y;
    const int t = threadIdx.x, wv = t >> 6, lane = t & 63;
    __shared__ float red[4];
    const float* w = f1w + (size_t)j * (2 * Dd);
    float a = 0.f;
    for (int k = t; k < Dd; k += 256) a += vpool[b * Dd + k] * w[k];
    for (int k = t; k < Dd; k += 256) a += tpool[b * Dd + k] * w[Dd + k];
    a = waveSum(a);
    if (lane == 0) red[wv] = a;
    __syncthreads();
    if (t == 0) hbuf[b * HIDh + j] = fmaxf(red[0] + red[1] + red[2] + red[3] + f1b[j], 0.0f);
}

// ---------------- FFN stage 2 ----------------
__global__ __launch_bounds__(256) void ffn2_kernel(
    const float* __restrict__ hbuf, const float* __restrict__ f2w,
    const float* __restrict__ f2b, float* __restrict__ lbuf)
{
    const int b = blockIdx.x;
    const int t = threadIdx.x, wv = t >> 6, lane = t & 63;
    __shared__ float red[4];
    float p = 0.f;
    for (int j = t; j < HIDh; j += 256) p += hbuf[b * HIDh + j] * f2w[j];
    p = waveSum(p);
    if (lane == 0) red[wv] = p;
    __syncthreads();
    if (t == 0) {
        const float z = red[0] + red[1] + red[2] + red[3] + f2b[0];
        lbuf[b] = 1.0f / (1.0f + expf(-z));
    }
}

// ---------------- sim softmax (bf16 scores) -> fp32 mask (1.0/0.0) ----------------
__global__ __launch_bounds__(256) void sim_softmax_mask(
    const u16* __restrict__ scores, const float* __restrict__ lbuf, float* __restrict__ maskF)
{
    const int row = blockIdx.x, b = blockIdx.y;
    const int t = threadIdx.x, wv = t >> 6, lane = t & 63;
    __shared__ float red[8];
    const size_t off = ((size_t)b * Mm + row) * Nn;
    const uint2 sv = *(const uint2*)(scores + off + 4 * t);
    const float x0 = bf2f((u16)(sv.x & 0xFFFFu)) * INV_SQRT_D;
    const float x1 = bf2f((u16)(sv.x >> 16))     * INV_SQRT_D;
    const float x2 = bf2f((u16)(sv.y & 0xFFFFu)) * INV_SQRT_D;
    const float x3 = bf2f((u16)(sv.y >> 16))     * INV_SQRT_D;
    float mx = waveMax(fmaxf(fmaxf(x0, x1), fmaxf(x2, x3)));
    if (lane == 0) red[wv] = mx;
    __syncthreads();
    mx = fmaxf(fmaxf(red[0], red[1]), fmaxf(red[2], red[3]));
    const float e0 = expf(x0 - mx), e1 = expf(x1 - mx), e2 = expf(x2 - mx), e3 = expf(x3 - mx);
    float s = waveSum(e0 + e1 + e2 + e3);
    if (lane == 0) red[4 + wv] = s;
    __syncthreads();
    const float inv = 1.0f / fmaxf(red[4] + red[5] + red[6] + red[7], 1e-30f);
    const float l = lbuf[b];
    float4 mk;
    mk.x = (e0 * inv >= l) ? 1.0f : 0.0f;
    mk.y = (e1 * inv >= l) ? 1.0f : 0.0f;
    mk.z = (e2 * inv >= l) ? 1.0f : 0.0f;
    mk.w = (e3 * inv >= l) ? 1.0f : 0.0f;
    *(float4*)(maskF + off + 4 * t) = mk;
}

// ---------------- masked softmax over bf16 scores, IN-PLACE -> bf16 attn ----------------
template <bool TRANSP>
__global__ __launch_bounds__(256) void masked_softmax(
    u16* __restrict__ scores, const u32* __restrict__ mask32)
{
    const int row = blockIdx.x, b = blockIdx.y;
    const int t = threadIdx.x, wv = t >> 6, lane = t & 63;
    __shared__ float red[8];
    const size_t off = ((size_t)b * Mm + row) * Nn;
    const uint2 sv = *(const uint2*)(scores + off + 4 * t);
    float x0 = bf2f((u16)(sv.x & 0xFFFFu)) * INV_SQRT_D;
    float x1 = bf2f((u16)(sv.x >> 16))     * INV_SQRT_D;
    float x2 = bf2f((u16)(sv.y & 0xFFFFu)) * INV_SQRT_D;
    float x3 = bf2f((u16)(sv.y >> 16))     * INV_SQRT_D;
    if (TRANSP) {
        const u32* mcol = mask32 + (size_t)b * Mm * Nn + row;
        if (!mcol[(size_t)(4 * t + 0) * Nn]) x0 = NEGINF;
        if (!mcol[(size_t)(4 * t + 1) * Nn]) x1 = NEGINF;
        if (!mcol[(size_t)(4 * t + 2) * Nn]) x2 = NEGINF;
        if (!mcol[(size_t)(4 * t + 3) * Nn]) x3 = NEGINF;
    } else {
        const u32* mrow = mask32 + off + 4 * t;
        if (!mrow[0]) x0 = NEGINF;
        if (!mrow[1]) x1 = NEGINF;
        if (!mrow[2]) x2 = NEGINF;
        if (!mrow[3]) x3 = NEGINF;
    }
    float mx = waveMax(fmaxf(fmaxf(x0, x1), fmaxf(x2, x3)));
    if (lane == 0) red[wv] = mx;
    __syncthreads();
    mx = fmaxf(fmaxf(red[0], red[1]), fmaxf(red[2], red[3]));
    const float e0 = expf(x0 - mx), e1 = expf(x1 - mx), e2 = expf(x2 - mx), e3 = expf(x3 - mx);
    float s = waveSum(e0 + e1 + e2 + e3);
    if (lane == 0) red[4 + wv] = s;
    __syncthreads();
    const float inv = 1.0f / fmaxf(red[4] + red[5] + red[6] + red[7], 1e-30f);
    uint2 pk;
    pk.x = (u32)f2bf(e0 * inv) | ((u32)f2bf(e1 * inv) << 16);
    pk.y = (u32)f2bf(e2 * inv) | ((u32)f2bf(e3 * inv) << 16);
    *(uint2*)(scores + off + 4 * t) = pk;
}

extern "C" void kernel_launch(void* const* d_in, const int* in_sizes, int n_in,
                              void* d_out, int out_size, void* d_ws, size_t ws_size,
                              hipStream_t stream)
{
    (void)in_sizes; (void)n_in; (void)out_size; (void)ws_size;
    const float* oV     = (const float*)d_in[0];
    const float* oT     = (const float*)d_in[1];
    const float* Wq_v_w = (const float*)d_in[2];
    const float* Wq_v_b = (const float*)d_in[3];
    const float* Wk_t_w = (const float*)d_in[4];
    const float* Wk_t_b = (const float*)d_in[5];
    const float* Wv_t_w = (const float*)d_in[6];
    const float* Wv_t_b = (const float*)d_in[7];
    const float* Wq_t_w = (const float*)d_in[8];
    const float* Wq_t_b = (const float*)d_in[9];
    const float* Wk_v_w = (const float*)d_in[10];
    const float* Wk_v_b = (const float*)d_in[11];
    const float* Wv_v_w = (const float*)d_in[12];
    const float* Wv_v_b = (const float*)d_in[13];
    const float* f1w    = (const float*)d_in[14];
    const float* f1b    = (const float*)d_in[15];
    const float* f2w    = (const float*)d_in[16];
    const float* f2b    = (const float*)d_in[17];

    // d_out: fp32, three regions of BMD elements each
    float* out_vt = (float*)d_out;
    float* out_tv = out_vt + BMDc;
    float* maskF  = out_vt + 2 * BMDc;

    // ws: 4 bf16 slots = 128 MB (proven budget)
    u16* S0 = (u16*)d_ws;        // Q projection
    u16* S1 = S0 + BMDc;         // K projection
    u16* S2 = S1 + BMDc;         // V^T projection
    u16* S3 = S2 + BMDc;         // scores / attn (in-place)
    // oVb/oTb live in the out_tv region (64MB): dead after the last projection (step 13),
    // before PV2 writes out_tv (step 16).
    u16* oVb = (u16*)out_tv;
    u16* oTb = oVb + BMDc;
    // small scratch in out_vt region (dead before PV1 writes out_vt)
    float* vpool = out_vt;
    float* tpool = vpool + Bz * Dd;
    float* hbuf  = tpool + Bz * Dd;
    float* lbuf  = hbuf + Bz * HIDh;

    const dim3 blk(256);
    const dim3 gBat(Mm / 128, Nn / 128, Bz);     // batched 1024^3 GEMMs
    const dim3 gProj(Bz * Mm / 128, Dd / 128, 1);
    const dim3 gRow(Mm, Bz);
    const long sMD = sMDc, sMN = (long)Mm * Nn;

    // 0: convert oV/oT to bf16 (into out_tv region)
    conv_kernel<<<dim3(4096), blk, 0, stream>>>(oV, oVb, BMDc / 8);
    conv_kernel<<<dim3(4096), blk, 0, stream>>>(oT, oTb, BMDc / 8);

    // 1-2: pools (atomic partials; zero-init) + threshold l
    hipMemsetAsync(vpool, 0, 2 * Bz * Dd * sizeof(float), stream);
    pool_kernel<<<dim3(Dd / 256, Bz, 8), blk, 0, stream>>>(oV, oT, vpool, tpool);
    ffn1_kernel<<<dim3(HIDh, Bz), blk, 0, stream>>>(vpool, tpool, f1w, f1b, hbuf);
    ffn2_kernel<<<dim3(Bz), blk, 0, stream>>>(hbuf, f2w, f2b, lbuf);

    // 3-4: sim scores (bf16 -> S3) -> fp32 mask
    gemm_bt_async<false><<<gBat, blk, 0, stream>>>(oVb, oTb, S3, Dd, Nn, sMD, sMD, sMN);
    sim_softmax_mask<<<gRow, blk, 0, stream>>>(S3, lbuf, maskF);

    // 5-10: V->T.  Qv->S0, Kt->S1, Vt^T->S2.
    gemm_proj<false><<<gProj, blk, 0, stream>>>(oVb, Wq_v_w, Wq_v_b, S0, Dd);
    gemm_proj<false><<<gProj, blk, 0, stream>>>(oTb, Wk_t_w, Wk_t_b, S1, Dd);
    gemm_proj<true ><<<gProj, blk, 0, stream>>>(oTb, Wv_t_w, Wv_t_b, S2, Dd);
    gemm_bt_async<false><<<gBat, blk, 0, stream>>>(S0, S1, S3, Dd, Nn, sMD, sMD, sMN);
    masked_softmax<false><<<gRow, blk, 0, stream>>>(S3, (const u32*)maskF);
    gemm_bt_async<true><<<gBat, blk, 0, stream>>>(S3, S2, out_vt, Nn, Dd, sMN, sMD, sMD);

    // 11-16: T->V.  Qt->S0, Kv->S1, Vv^T->S2.  (last oVb/oTb uses; then PV2 may overwrite out_tv)
    gemm_proj<false><<<gProj, blk, 0, stream>>>(oTb, Wq_t_w, Wq_t_b, S0, Dd);
    gemm_proj<false><<<gProj, blk, 0, stream>>>(oVb, Wk_v_w, Wk_v_b, S1, Dd);
    gemm_proj<true ><<<gProj, blk, 0, stream>>>(oVb, Wv_v_w, Wv_v_b, S2, Dd);
    gemm_bt_async<false><<<gBat, blk, 0, stream>>>(S0, S1, S3, Dd, Nn, sMD, sMD, sMN);
    masked_softmax<true><<<gRow, blk, 0, stream>>>(S3, (const u32*)maskF);
    gemm_bt_async<true><<<gBat, blk, 0, stream>>>(S3, S2, out_tv, Nn, Dd, sMN, sMD, sMD);
}

// Round 7
// 1124.941 us; speedup vs baseline: 2.5794x; 1.0493x over previous
//
#include <hip/hip_runtime.h>
#include <stdint.h>

typedef unsigned short u16;
typedef unsigned char  u8;
typedef unsigned int   u32;
typedef __attribute__((ext_vector_type(8))) short  short8;
typedef __attribute__((ext_vector_type(4))) float  floatx4;

#define Bz   16
#define Mm   1024
#define Nn   1024
#define Dd   1024
#define HIDh 512
#define INV_SQRT_D 0.03125f
#define NEGINF (-1.0e9f)
#define BMDc  ((size_t)Bz * Mm * Dd)
#define sMDc  ((long)Mm * Dd)

__device__ __forceinline__ float bf2f(u16 h) {
    union { u32 u; float f; } c; c.u = ((u32)h) << 16; return c.f;
}
__device__ __forceinline__ u16 f2bf(float f) {
    union { float f; u32 u; } c; c.f = f;
    u32 u = c.u;
    return (u16)((u + 0x7FFFu + ((u >> 16) & 1u)) >> 16);
}
// async global->LDS, 16B/lane; lds ptr must be wave-uniform (HW adds lane*16)
__device__ __forceinline__ void g2lds16(const u16* g, u16* l) {
    __builtin_amdgcn_global_load_lds((const __attribute__((address_space(1))) void*)g,
                                     (__attribute__((address_space(3))) void*)l, 16, 0, 0);
}

__device__ __forceinline__ float waveSum(float v) {
#pragma unroll
    for (int o = 32; o > 0; o >>= 1) v += __shfl_xor(v, o);
    return v;
}
__device__ __forceinline__ float waveMax(float v) {
#pragma unroll
    for (int o = 32; o > 0; o >>= 1) v = fmaxf(v, __shfl_xor(v, o));
    return v;
}

// ============ C = A * B^T, bf16 A/B via async LDS staging (m97 recipe) ============
template <bool OUT_FP32>
__global__ __launch_bounds__(256, 2) void gemm_bt_async(
    const u16* __restrict__ A, const u16* __restrict__ Bm,
    void* __restrict__ Cv, int K, int ldc, long sA, long sB, long sC)
{
    __shared__ __align__(16) u16 lA[128 * 32];
    __shared__ __align__(16) u16 lB[128 * 32];
    const int tid = threadIdx.x;
    const int lane = tid & 63;
    const int fr = lane & 15, fq = lane >> 4;
    const int wv = tid >> 6;
    const int tileM = blockIdx.x * 128, tileN = blockIdx.y * 128;
    A  += (long)blockIdx.z * sA;
    Bm += (long)blockIdx.z * sB;

    floatx4 acc[4][4];
#pragma unroll
    for (int i = 0; i < 4; ++i)
#pragma unroll
        for (int j = 0; j < 4; ++j) acc[i][j] = (floatx4){0.f, 0.f, 0.f, 0.f};

    const int waveM = (wv >> 1) * 64, waveN = (wv & 1) * 64;

    for (int k0 = 0; k0 < K; k0 += 32) {
        __syncthreads();
#pragma unroll
        for (int i = 0; i < 2; ++i) {
            const int chunk = i * 256 + tid;   // 16B chunk id, row-major [128][32]
            const int r = chunk >> 2, c = (chunk & 3) << 3;
            const int wbase = (i * 256 + wv * 64) * 8;
            g2lds16(A  + (size_t)(tileM + r) * K + (k0 + c), &lA[wbase]);
            g2lds16(Bm + (size_t)(tileN + r) * K + (k0 + c), &lB[wbase]);
        }
        __syncthreads();
        short8 af[4], bf[4];
#pragma unroll
        for (int i = 0; i < 4; ++i)
            af[i] = *(const short8*)&lA[(waveM + i * 16 + fr) * 32 + fq * 8];
#pragma unroll
        for (int j = 0; j < 4; ++j)
            bf[j] = *(const short8*)&lB[(waveN + j * 16 + fr) * 32 + fq * 8];
#pragma unroll
        for (int i = 0; i < 4; ++i)
#pragma unroll
            for (int j = 0; j < 4; ++j)
                acc[i][j] = __builtin_amdgcn_mfma_f32_16x16x32_bf16(af[i], bf[j], acc[i][j], 0, 0, 0);
    }

    if (OUT_FP32) {
        float* C = (float*)Cv + (long)blockIdx.z * sC;
#pragma unroll
        for (int j = 0; j < 4; ++j) {
            const int col = tileN + waveN + j * 16 + fr;
#pragma unroll
            for (int i = 0; i < 4; ++i) {
                const int row0 = tileM + waveM + i * 16 + fq * 4;
#pragma unroll
                for (int r = 0; r < 4; ++r)
                    C[(size_t)(row0 + r) * ldc + col] = acc[i][j][r];
            }
        }
    } else {
        u16* C = (u16*)Cv + (long)blockIdx.z * sC;
#pragma unroll
        for (int j = 0; j < 4; ++j) {
            const int col = tileN + waveN + j * 16 + fr;
#pragma unroll
            for (int i = 0; i < 4; ++i) {
                const int row0 = tileM + waveM + i * 16 + fq * 4;
#pragma unroll
                for (int r = 0; r < 4; ++r)
                    C[(size_t)(row0 + r) * ldc + col] = f2bf(acc[i][j][r]);
            }
        }
    }
}

// ============ Projection: C = A * W^T + bias.  A bf16 (async), W fp32 (reg-convert) ============
template <bool TRANSC>
__global__ __launch_bounds__(256, 2) void gemm_proj(
    const u16* __restrict__ A, const float* __restrict__ Wf, const float* __restrict__ bias,
    u16* __restrict__ C, int K)
{
    __shared__ __align__(16) u16 lA[128 * 32];
    __shared__ __align__(16) u16 lB[128 * 32];
    const int tid = threadIdx.x;
    const int lane = tid & 63;
    const int fr = lane & 15, fq = lane >> 4;
    const int wv = tid >> 6;
    const int tileM = blockIdx.x * 128, tileN = blockIdx.y * 128;

    floatx4 acc[4][4];
#pragma unroll
    for (int i = 0; i < 4; ++i)
#pragma unroll
        for (int j = 0; j < 4; ++j) acc[i][j] = (floatx4){0.f, 0.f, 0.f, 0.f};

    const int waveM = (wv >> 1) * 64, waveN = (wv & 1) * 64;

    for (int k0 = 0; k0 < K; k0 += 32) {
        float4 rb[2][2];
#pragma unroll
        for (int i = 0; i < 2; ++i) {
            const int chunk = i * 256 + tid;
            const int r = chunk >> 2, c = (chunk & 3) << 3;
            const float* p = Wf + (size_t)(tileN + r) * K + (k0 + c);
            rb[i][0] = *(const float4*)p; rb[i][1] = *(const float4*)(p + 4);
        }
        __syncthreads();
#pragma unroll
        for (int i = 0; i < 2; ++i) {
            const int chunk = i * 256 + tid;
            const int r = chunk >> 2, c = (chunk & 3) << 3;
            const int wbase = (i * 256 + wv * 64) * 8;
            g2lds16(A + (size_t)(tileM + r) * K + (k0 + c), &lA[wbase]);
            (void)r; (void)c;
        }
#pragma unroll
        for (int i = 0; i < 2; ++i) {
            const int chunk = i * 256 + tid;
            const int r = chunk >> 2, c = (chunk & 3) << 3;
            short8 sb;
            sb[0]=(short)f2bf(rb[i][0].x); sb[1]=(short)f2bf(rb[i][0].y);
            sb[2]=(short)f2bf(rb[i][0].z); sb[3]=(short)f2bf(rb[i][0].w);
            sb[4]=(short)f2bf(rb[i][1].x); sb[5]=(short)f2bf(rb[i][1].y);
            sb[6]=(short)f2bf(rb[i][1].z); sb[7]=(short)f2bf(rb[i][1].w);
            *(short8*)&lB[r * 32 + c] = sb;
        }
        __syncthreads();
        short8 af[4], bf[4];
#pragma unroll
        for (int i = 0; i < 4; ++i)
            af[i] = *(const short8*)&lA[(waveM + i * 16 + fr) * 32 + fq * 8];
#pragma unroll
        for (int j = 0; j < 4; ++j)
            bf[j] = *(const short8*)&lB[(waveN + j * 16 + fr) * 32 + fq * 8];
#pragma unroll
        for (int i = 0; i < 4; ++i)
#pragma unroll
            for (int j = 0; j < 4; ++j)
                acc[i][j] = __builtin_amdgcn_mfma_f32_16x16x32_bf16(af[i], bf[j], acc[i][j], 0, 0, 0);
    }

#pragma unroll
    for (int j = 0; j < 4; ++j) {
        const int col = tileN + waveN + j * 16 + fr;
        const float bv = bias[col];
#pragma unroll
        for (int i = 0; i < 4; ++i) {
            const int row0 = tileM + waveM + i * 16 + fq * 4;
#pragma unroll
            for (int r = 0; r < 4; ++r) {
                const int row = row0 + r;
                if (TRANSC) {
                    const int b = row >> 10, mloc = row & 1023;
                    C[(size_t)b * sMDc + (size_t)col * Mm + mloc] = f2bf(acc[i][j][r] + bv);
                } else {
                    C[(size_t)row * Dd + col] = f2bf(acc[i][j][r] + bv);
                }
            }
        }
    }
}

// ---------------- fp32 -> bf16 conversion ----------------
__global__ __launch_bounds__(256) void conv_kernel(
    const float* __restrict__ src, u16* __restrict__ dst, size_t n8)
{
    const size_t stride = (size_t)gridDim.x * 256;
    for (size_t i = (size_t)blockIdx.x * 256 + threadIdx.x; i < n8; i += stride) {
        const float4 a = ((const float4*)src)[2 * i];
        const float4 b = ((const float4*)src)[2 * i + 1];
        short8 o;
        o[0]=(short)f2bf(a.x); o[1]=(short)f2bf(a.y); o[2]=(short)f2bf(a.z); o[3]=(short)f2bf(a.w);
        o[4]=(short)f2bf(b.x); o[5]=(short)f2bf(b.y); o[6]=(short)f2bf(b.z); o[7]=(short)f2bf(b.w);
        *(short8*)(dst + 8 * i) = o;
    }
}

// ---------------- pooling ----------------
__global__ __launch_bounds__(256) void pool_kernel(
    const float* __restrict__ oV, const float* __restrict__ oT,
    float* __restrict__ vpool, float* __restrict__ tpool)
{
    const int col = blockIdx.x * 256 + threadIdx.x;
    const int b = blockIdx.y;
    const int src_i = blockIdx.z & 1, chunk = blockIdx.z >> 1;
    const float* src = (src_i ? oT : oV) + (size_t)b * Mm * Dd;
    const int r0 = chunk * (Mm / 4);
    float s = 0.f;
    for (int r = r0; r < r0 + Mm / 4; ++r) s += src[(size_t)r * Dd + col];
    float* dst = src_i ? tpool : vpool;
    atomicAdd(dst + b * Dd + col, s * (1.0f / Mm));
}

// ---------------- FFN ----------------
__global__ __launch_bounds__(256) void ffn1_kernel(
    const float* __restrict__ vpool, const float* __restrict__ tpool,
    const float* __restrict__ f1w, const float* __restrict__ f1b,
    float* __restrict__ hbuf)
{
    const int j = blockIdx.x, b = blockIdx.y;
    const int t = threadIdx.x, wv = t >> 6, lane = t & 63;
    __shared__ float red[4];
    const float* w = f1w + (size_t)j * (2 * Dd);
    float a = 0.f;
    for (int k = t; k < Dd; k += 256) a += vpool[b * Dd + k] * w[k];
    for (int k = t; k < Dd; k += 256) a += tpool[b * Dd + k] * w[Dd + k];
    a = waveSum(a);
    if (lane == 0) red[wv] = a;
    __syncthreads();
    if (t == 0) hbuf[b * HIDh + j] = fmaxf(red[0] + red[1] + red[2] + red[3] + f1b[j], 0.0f);
}

__global__ __launch_bounds__(256) void ffn2_kernel(
    const float* __restrict__ hbuf, const float* __restrict__ f2w,
    const float* __restrict__ f2b, float* __restrict__ lbuf)
{
    const int b = blockIdx.x;
    const int t = threadIdx.x, wv = t >> 6, lane = t & 63;
    __shared__ float red[4];
    float p = 0.f;
    for (int j = t; j < HIDh; j += 256) p += hbuf[b * HIDh + j] * f2w[j];
    p = waveSum(p);
    if (lane == 0) red[wv] = p;
    __syncthreads();
    if (t == 0) {
        const float z = red[0] + red[1] + red[2] + red[3] + f2b[0];
        lbuf[b] = 1.0f / (1.0f + expf(-z));
    }
}

// ---------------- sim softmax -> fp32 mask (d_out) ----------------
__global__ __launch_bounds__(256) void sim_softmax_mask(
    const u16* __restrict__ scores, const float* __restrict__ lbuf, float* __restrict__ maskF)
{
    const int row = blockIdx.x, b = blockIdx.y;
    const int t = threadIdx.x, wv = t >> 6, lane = t & 63;
    __shared__ float red[8];
    const size_t off = ((size_t)b * Mm + row) * Nn;
    const uint2 sv = *(const uint2*)(scores + off + 4 * t);
    const float x0 = bf2f((u16)(sv.x & 0xFFFFu)) * INV_SQRT_D;
    const float x1 = bf2f((u16)(sv.x >> 16))     * INV_SQRT_D;
    const float x2 = bf2f((u16)(sv.y & 0xFFFFu)) * INV_SQRT_D;
    const float x3 = bf2f((u16)(sv.y >> 16))     * INV_SQRT_D;
    float mx = waveMax(fmaxf(fmaxf(x0, x1), fmaxf(x2, x3)));
    if (lane == 0) red[wv] = mx;
    __syncthreads();
    mx = fmaxf(fmaxf(red[0], red[1]), fmaxf(red[2], red[3]));
    const float e0 = expf(x0 - mx), e1 = expf(x1 - mx), e2 = expf(x2 - mx), e3 = expf(x3 - mx);
    float s = waveSum(e0 + e1 + e2 + e3);
    if (lane == 0) red[4 + wv] = s;
    __syncthreads();
    const float inv = 1.0f / fmaxf(red[4] + red[5] + red[6] + red[7], 1e-30f);
    const float l = lbuf[b];
    float4 mk;
    mk.x = (e0 * inv >= l) ? 1.0f : 0.0f;
    mk.y = (e1 * inv >= l) ? 1.0f : 0.0f;
    mk.z = (e2 * inv >= l) ? 1.0f : 0.0f;
    mk.w = (e3 * inv >= l) ? 1.0f : 0.0f;
    *(float4*)(maskF + off + 4 * t) = mk;
}

// ---------------- mask transpose: fp32 mask[b][m][n] -> u8 maskT[b][n][m] ----------------
// 64x64 tiles via LDS; coalesced fp32 reads, coalesced 16B u8 writes.
__global__ __launch_bounds__(256) void transpose_mask(
    const float* __restrict__ maskF, u8* __restrict__ maskT)
{
    __shared__ u8 tile[64][68];   // +4 pad: LDS byte-gather stride 68 cycles banks
    const int m0 = blockIdx.x * 64, n0 = blockIdx.y * 64, b = blockIdx.z;
    const int t = threadIdx.x;
    const int r = t >> 2, c = (t & 3) * 16;
    const float* src = maskF + ((size_t)b * Mm + (m0 + r)) * Nn + n0 + c;
    float4 f0 = ((const float4*)src)[0];
    float4 f1 = ((const float4*)src)[1];
    float4 f2 = ((const float4*)src)[2];
    float4 f3 = ((const float4*)src)[3];
    u8* dst = &tile[r][c];
    dst[0]=f0.x!=0.f; dst[1]=f0.y!=0.f; dst[2]=f0.z!=0.f; dst[3]=f0.w!=0.f;
    dst[4]=f1.x!=0.f; dst[5]=f1.y!=0.f; dst[6]=f1.z!=0.f; dst[7]=f1.w!=0.f;
    dst[8]=f2.x!=0.f; dst[9]=f2.y!=0.f; dst[10]=f2.z!=0.f; dst[11]=f2.w!=0.f;
    dst[12]=f3.x!=0.f; dst[13]=f3.y!=0.f; dst[14]=f3.z!=0.f; dst[15]=f3.w!=0.f;
    __syncthreads();
    union { u8 b[16]; uint4 v; } pk;
#pragma unroll
    for (int k = 0; k < 16; ++k) pk.b[k] = tile[c + k][r];
    *(uint4*)(maskT + ((size_t)b * Nn + (n0 + r)) * Mm + m0 + c) = pk.v;
}

// ---------------- masked softmax over bf16 scores, IN-PLACE -> bf16 attn ----------------
// !TRANSP: mask from fp32 maskF row-major.  TRANSP: mask from u8 maskT (pre-transposed).
template <bool TRANSP>
__global__ __launch_bounds__(256) void masked_softmax(
    u16* __restrict__ scores, const float* __restrict__ maskF, const u8* __restrict__ maskT)
{
    const int row = blockIdx.x, b = blockIdx.y;
    const int t = threadIdx.x, wv = t >> 6, lane = t & 63;
    __shared__ float red[8];
    const size_t off = ((size_t)b * Mm + row) * Nn;
    const uint2 sv = *(const uint2*)(scores + off + 4 * t);
    float x0 = bf2f((u16)(sv.x & 0xFFFFu)) * INV_SQRT_D;
    float x1 = bf2f((u16)(sv.x >> 16))     * INV_SQRT_D;
    float x2 = bf2f((u16)(sv.y & 0xFFFFu)) * INV_SQRT_D;
    float x3 = bf2f((u16)(sv.y >> 16))     * INV_SQRT_D;
    if (TRANSP) {
        const u32 mk = *(const u32*)(maskT + off + 4 * t);   // 4 u8 flags, coalesced
        if (!(mk & 0x000000FFu)) x0 = NEGINF;
        if (!(mk & 0x0000FF00u)) x1 = NEGINF;
        if (!(mk & 0x00FF0000u)) x2 = NEGINF;
        if (!(mk & 0xFF000000u)) x3 = NEGINF;
    } else {
        const float4 mk = *(const float4*)(maskF + off + 4 * t);
        if (mk.x == 0.f) x0 = NEGINF;
        if (mk.y == 0.f) x1 = NEGINF;
        if (mk.z == 0.f) x2 = NEGINF;
        if (mk.w == 0.f) x3 = NEGINF;
    }
    float mx = waveMax(fmaxf(fmaxf(x0, x1), fmaxf(x2, x3)));
    if (lane == 0) red[wv] = mx;
    __syncthreads();
    mx = fmaxf(fmaxf(red[0], red[1]), fmaxf(red[2], red[3]));
    const float e0 = expf(x0 - mx), e1 = expf(x1 - mx), e2 = expf(x2 - mx), e3 = expf(x3 - mx);
    float s = waveSum(e0 + e1 + e2 + e3);
    if (lane == 0) red[4 + wv] = s;
    __syncthreads();
    const float inv = 1.0f / fmaxf(red[4] + red[5] + red[6] + red[7], 1e-30f);
    uint2 pk;
    pk.x = (u32)f2bf(e0 * inv) | ((u32)f2bf(e1 * inv) << 16);
    pk.y = (u32)f2bf(e2 * inv) | ((u32)f2bf(e3 * inv) << 16);
    *(uint2*)(scores + off + 4 * t) = pk;
}

extern "C" void kernel_launch(void* const* d_in, const int* in_sizes, int n_in,
                              void* d_out, int out_size, void* d_ws, size_t ws_size,
                              hipStream_t stream)
{
    (void)in_sizes; (void)n_in; (void)out_size; (void)ws_size;
    const float* oV     = (const float*)d_in[0];
    const float* oT     = (const float*)d_in[1];
    const float* Wq_v_w = (const float*)d_in[2];
    const float* Wq_v_b = (const float*)d_in[3];
    const float* Wk_t_w = (const float*)d_in[4];
    const float* Wk_t_b = (const float*)d_in[5];
    const float* Wv_t_w = (const float*)d_in[6];
    const float* Wv_t_b = (const float*)d_in[7];
    const float* Wq_t_w = (const float*)d_in[8];
    const float* Wq_t_b = (const float*)d_in[9];
    const float* Wk_v_w = (const float*)d_in[10];
    const float* Wk_v_b = (const float*)d_in[11];
    const float* Wv_v_w = (const float*)d_in[12];
    const float* Wv_v_b = (const float*)d_in[13];
    const float* f1w    = (const float*)d_in[14];
    const float* f1b    = (const float*)d_in[15];
    const float* f2w    = (const float*)d_in[16];
    const float* f2b    = (const float*)d_in[17];

    float* out_vt = (float*)d_out;
    float* out_tv = out_vt + BMDc;
    float* maskF  = out_vt + 2 * BMDc;

    // ws (768 MiB available): everything lives here now.
    u16* S0  = (u16*)d_ws;            // Q projection        32 MB
    u16* S1  = S0 + BMDc;             // K projection        32 MB
    u16* S2  = S1 + BMDc;             // V^T projection      32 MB
    u16* S3  = S2 + BMDc;             // scores/attn         32 MB
    u16* oVb = S3 + BMDc;             // bf16 oV             32 MB
    u16* oTb = oVb + BMDc;            // bf16 oT             32 MB
    u8*  maskT = (u8*)(oTb + BMDc);   // transposed u8 mask  16 MB
    float* vpool = (float*)(maskT + BMDc);
    float* tpool = vpool + Bz * Dd;
    float* hbuf  = tpool + Bz * Dd;
    float* lbuf  = hbuf + Bz * HIDh;

    const dim3 blk(256);
    const dim3 gBat(Mm / 128, Nn / 128, Bz);
    const dim3 gProj(Bz * Mm / 128, Dd / 128, 1);
    const dim3 gRow(Mm, Bz);
    const dim3 gTrp(Mm / 64, Nn / 64, Bz);
    const long sMD = sMDc, sMN = (long)Mm * Nn;

    // 0: convert oV/oT to bf16
    conv_kernel<<<dim3(4096), blk, 0, stream>>>(oV, oVb, BMDc / 8);
    conv_kernel<<<dim3(4096), blk, 0, stream>>>(oT, oTb, BMDc / 8);

    // 1-2: pools + threshold l
    hipMemsetAsync(vpool, 0, 2 * Bz * Dd * sizeof(float), stream);
    pool_kernel<<<dim3(Dd / 256, Bz, 8), blk, 0, stream>>>(oV, oT, vpool, tpool);
    ffn1_kernel<<<dim3(HIDh, Bz), blk, 0, stream>>>(vpool, tpool, f1w, f1b, hbuf);
    ffn2_kernel<<<dim3(Bz), blk, 0, stream>>>(hbuf, f2w, f2b, lbuf);

    // 3-4: sim scores -> mask (fp32 out) -> transposed u8 mask
    gemm_bt_async<false><<<gBat, blk, 0, stream>>>(oVb, oTb, S3, Dd, Nn, sMD, sMD, sMN);
    sim_softmax_mask<<<gRow, blk, 0, stream>>>(S3, lbuf, maskF);
    transpose_mask<<<gTrp, blk, 0, stream>>>(maskF, maskT);

    // 5-10: V->T.  Qv->S0, Kt->S1, Vt^T->S2.
    gemm_proj<false><<<gProj, blk, 0, stream>>>(oVb, Wq_v_w, Wq_v_b, S0, Dd);
    gemm_proj<false><<<gProj, blk, 0, stream>>>(oTb, Wk_t_w, Wk_t_b, S1, Dd);
    gemm_proj<true ><<<gProj, blk, 0, stream>>>(oTb, Wv_t_w, Wv_t_b, S2, Dd);
    gemm_bt_async<false><<<gBat, blk, 0, stream>>>(S0, S1, S3, Dd, Nn, sMD, sMD, sMN);
    masked_softmax<false><<<gRow, blk, 0, stream>>>(S3, maskF, maskT);
    gemm_bt_async<true><<<gBat, blk, 0, stream>>>(S3, S2, out_vt, Nn, Dd, sMN, sMD, sMD);

    // 11-16: T->V.  Qt->S0, Kv->S1, Vv^T->S2.
    gemm_proj<false><<<gProj, blk, 0, stream>>>(oTb, Wq_t_w, Wq_t_b, S0, Dd);
    gemm_proj<false><<<gProj, blk, 0, stream>>>(oVb, Wk_v_w, Wk_v_b, S1, Dd);
    gemm_proj<true ><<<gProj, blk, 0, stream>>>(oVb, Wv_v_w, Wv_v_b, S2, Dd);
    gemm_bt_async<false><<<gBat, blk, 0, stream>>>(S0, S1, S3, Dd, Nn, sMD, sMD, sMN);
    masked_softmax<true><<<gRow, blk, 0, stream>>>(S3, maskF, maskT);
    gemm_bt_async<true><<<gBat, blk, 0, stream>>>(S3, S2, out_tv, Nn, Dd, sMN, sMD, sMD);
}